// Round 7
// baseline (110.367 us; speedup 1.0000x reference)
//
#include <hip/hip_runtime.h>
#include <hip/hip_bf16.h>
#include <math.h>

// Problem constants (fixed by reference setup_inputs)
#define BHALF 4096          // B
#define NROW 8192           // 2B
#define DIM 128             // D
#define INV_T 10.0f         // 1/temperature
#define K1 14.4269504088896f  // INV_T*log2(e): exp((v-1)*10) = 2^(v*K1 - K1)

typedef short bf16x8 __attribute__((ext_vector_type(8)));   // 8 bf16 = 4 VGPRs
typedef float f32x4  __attribute__((ext_vector_type(4)));   // C/D frag

typedef const __attribute__((address_space(1))) void ga_void;
typedef __attribute__((address_space(3))) void ls_void;

// ---------------------------------------------------------------------------
// Kernel 1: row-normalize concat(view1, view2) -> e_bf16 (NROW x DIM);
// zero d_out + the two partial half-slices sim never writes.
// ---------------------------------------------------------------------------
__global__ __launch_bounds__(256) void normalize_kernel(
    const float* __restrict__ v1, const float* __restrict__ v2,
    __hip_bfloat16* __restrict__ e, float* __restrict__ rowpart,
    float* __restrict__ colpart, float* __restrict__ out) {
  int row  = blockIdx.x * 4 + (threadIdx.x >> 6);
  int lane = threadIdx.x & 63;
  const float* src = (row < BHALF) ? (v1 + (size_t)row * DIM)
                                   : (v2 + (size_t)(row - BHALF) * DIM);
  float2 x = ((const float2*)src)[lane];
  float ss = x.x * x.x + x.y * x.y;
#pragma unroll
  for (int off = 32; off > 0; off >>= 1) ss += __shfl_down(ss, off);
  ss = __shfl(ss, 0);
  float s = 1.0f / fmaxf(sqrtf(ss), 1e-8f);
  ((__hip_bfloat162*)(e + (size_t)row * DIM))[lane] =
      __float22bfloat162_rn(make_float2(x.x * s, x.y * s));
  // h=8 blocks (d=32) only cover rows<4096 and cols>=4096:
  const int t = blockIdx.x * 256 + threadIdx.x;
  if (t < 4096) {
    rowpart[(size_t)8 * NROW + 4096 + t] = 0.0f;
    colpart[(size_t)31 * NROW + t] = 0.0f;
  }
  if (t == 0) out[0] = 0.0f;
}

// ---------------------------------------------------------------------------
// Stage one 128-col strip of e (128 rows x 256 B) into LDS via
// global_load_lds(16B). LDS layout: [128 rows][16 chunks of 16B], chunk
// index XOR-swizzled by (row&15). LDS dest LINEAR (wave-uniform base +
// lane*16, rule #21); swizzle via permuted per-lane GLOBAL source chunk.
// Each wave stages 32 rows (verified R7-R11).
// ---------------------------------------------------------------------------
__device__ __forceinline__ void stage_strip(const ushort* __restrict__ eC,
                                            ushort* BsBuf, int wave, int lane) {
#pragma unroll
  for (int j = 0; j < 8; ++j) {
    const int row    = wave * 32 + j * 4 + (lane >> 4);
    const int gchunk = (lane & 15) ^ (row & 15);
    const ushort* g  = eC + row * DIM + gchunk * 8;
    ushort* l        = BsBuf + (wave * 32 + j * 4) * 128;  // wave-uniform base
    __builtin_amdgcn_global_load_lds((ga_void*)g, (ls_void*)l, 16, 0, 0);
  }
}

// ---------------------------------------------------------------------------
// One 128x128 tile sweep, fully unrolled; NO cross-lane ops inside (R10 PMC:
// the per-sub csum shuffles were 4.26M conflict cycles + a ~100cyc serial
// chain per sub). csum kept in 8 per-sub registers, reduced by the CALLER
// once per tile. Diagonal fragment (sub==2*wave+rf) scalar-guarded.
// ---------------------------------------------------------------------------
__device__ __forceinline__ void sweep_tile(
    const ushort* __restrict__ Bs, const bf16x8 (&a_frag)[2][4],
    float (&rsum)[2][4], float (&csum)[8], const int (&chunkOff)[4],
    bool domask, bool dopos, int wave, int n, int quad, int rowStrip,
    int colBase, float* __restrict__ posv) {
#pragma unroll
  for (int sub = 0; sub < 8; ++sub) {
    const ushort* bp = Bs + (sub * 16 + n) * 128;
    bf16x8 b[4];
#pragma unroll
    for (int kk = 0; kk < 4; ++kk) b[kk] = *(const bf16x8*)(bp + chunkOff[kk]);
#pragma unroll
    for (int rf = 0; rf < 2; ++rf) {
      f32x4 acc = {0.f, 0.f, 0.f, 0.f};
#pragma unroll
      for (int kk = 0; kk < 4; ++kk)
        acc = __builtin_amdgcn_mfma_f32_16x16x32_bf16(a_frag[rf][kk], b[kk],
                                                      acc, 0, 0, 0);
      // C layout: row = quad*4 + reg, col = lane&15 (m89/m91 verified).
      if ((domask | dopos) && sub == 2 * wave + rf) {
        // Fragment carrying the tile-local diagonal (wave-uniform guard).
#pragma unroll
        for (int rr = 0; rr < 4; ++rr) {
          const float val = acc[rr];
          const float ex = __builtin_amdgcn_exp2f(__builtin_fmaf(val, K1, -K1));
          const bool hit = (n == quad * 4 + rr);
          if (domask) {
            rsum[rf][rr] += hit ? 0.0f : ex;   // mask self-similarity
          } else {                              // dopos: weight 2 + posv
            const float exw = hit ? 2.0f * ex : ex;
            rsum[rf][rr] += exw;
            csum[sub] += exw;
            if (hit) {
              posv[rowStrip * 128 + wave * 32 + rf * 16 + quad * 4 + rr] = val;
              posv[colBase + sub * 16 + n] = val;   // partner j = i + 4096
            }
          }
        }
      } else {
#pragma unroll
        for (int rr = 0; rr < 4; ++rr) {
          const float ex =
              __builtin_amdgcn_exp2f(__builtin_fmaf(acc[rr], K1, -K1));
          rsum[rf][rr] += ex;
          csum[sub] += ex;
        }
      }
    }
  }
}

// ---------------------------------------------------------------------------
// Kernel 2: symmetric sim + exp-sum partials, zero atomics.
// Grid (64, 9): h<8 -> block (r,h) sweeps d = 4h..4h+3 (c=(r+d)&63), exactly
// 4 tiles each; h==8 (r<32 only) -> the single partner tile d=32. 2080 tile
// sweeps total (the full symmetric cover). LDS = 32KB strip + 2KB colred =
// 34KB -> 4 blocks/CU = 4 waves/SIMD (R10/R11 lesson: cross-block TLP is
// the latency-hiding mechanism; 2 blocks/CU starves it). Single-buffered
// strip, 2 barriers/tile; DMA exposure hidden by the other 3 blocks/CU.
// Row sums -> rowpart[h][row]; col sums -> colpart[d-1][col] (unique slots).
// ---------------------------------------------------------------------------
__global__ __launch_bounds__(256, 4) void sim_kernel(
    const ushort* __restrict__ e, float* __restrict__ rowpart,
    float* __restrict__ colpart, float* __restrict__ posv) {
  const int r = blockIdx.x;
  const int h = blockIdx.y;
  if (h == 8 && r >= 32) return;   // uniform: whole block exits, no barrier hazard

  __shared__ ushort Bs[128 * 128] __attribute__((aligned(16)));
  __shared__ float colred[4][8][16];

  const int tid  = threadIdx.x;
  const int wave = tid >> 6;
  const int lane = tid & 63;
  const int n    = lane & 15;
  const int quad = lane >> 4;

  // Per-lane swizzled LDS chunk offsets (ushort units):
  int chunkOff[4];
#pragma unroll
  for (int kk = 0; kk < 4; ++kk)
    chunkOff[kk] = (((quad + 4 * kk) ^ n) * 8);

  // A fragments: 2 row-frags x 4 k-steps, register-resident.
  bf16x8 a_frag[2][4];
  const int rowWave = r * 128 + wave * 32;
#pragma unroll
  for (int rf = 0; rf < 2; ++rf) {
    const ushort* rp = e + (size_t)(rowWave + rf * 16 + n) * DIM + quad * 8;
#pragma unroll
    for (int kk = 0; kk < 4; ++kk)
      a_frag[rf][kk] = *(const bf16x8*)(rp + kk * 32);
  }

  float rsum[2][4] = {{0.f, 0.f, 0.f, 0.f}, {0.f, 0.f, 0.f, 0.f}};
  const int NT = (h == 8) ? 1 : 4;

#pragma unroll 1
  for (int i = 0; i < NT; ++i) {
    const int d = (h == 8) ? 32 : 4 * h + i;
    const int c = (r + d) & 63;
    stage_strip(e + (size_t)c * 128 * DIM, Bs, wave, lane);
    __syncthreads();   // DMA complete (syncthreads drains vmcnt)

    float csum[8] = {0.f, 0.f, 0.f, 0.f, 0.f, 0.f, 0.f, 0.f};
    sweep_tile(Bs, a_frag, rsum, csum, chunkOff, d == 0, d == 32, wave, n,
               quad, r, c * 128, posv);

    if (d != 0) {
      // 16 independent 2-deep shuffle chains (once per tile, not per sub).
#pragma unroll
      for (int sub = 0; sub < 8; ++sub) {
        float v = csum[sub];
        v += __shfl_xor(v, 16);
        v += __shfl_xor(v, 32);
        if (lane < 16) colred[wave][sub][n] = v;
      }
    }
    __syncthreads();   // all Bs reads done + colred visible
    if (d != 0 && tid < 128) {
      const int sub = tid >> 4, nn = tid & 15;
      const float s = colred[0][sub][nn] + colred[1][sub][nn] +
                      colred[2][sub][nn] + colred[3][sub][nn];
      colpart[(size_t)(d - 1) * NROW + c * 128 + tid] = s;
    }
    // next stage_strip's DMA (top of loop) vs the colred reads above:
    // both drain at the next __syncthreads before any reuse.
  }

  // Row sums: reduce across the 16 col-lanes, direct store (unique slot).
#pragma unroll
  for (int rf = 0; rf < 2; ++rf)
#pragma unroll
    for (int rr = 0; rr < 4; ++rr) {
      float v = rsum[rf][rr];
      v += __shfl_xor(v, 1);
      v += __shfl_xor(v, 2);
      v += __shfl_xor(v, 4);
      v += __shfl_xor(v, 8);
      if (n == 0)
        rowpart[(size_t)h * NROW + rowWave + rf * 16 + quad * 4 + rr] = v;
    }
}

// ---------------------------------------------------------------------------
// Kernel 3: S_i = sum_{h<9} rowpart[h][i] + sum_{s<32} colpart[s][i];
// loss_i = log(S_i) + (1-pos_i)/T ; out = mean (32 atomic partials).
// ---------------------------------------------------------------------------
__global__ __launch_bounds__(256) void finalize_kernel(
    const float* __restrict__ rowpart, const float* __restrict__ colpart,
    const float* __restrict__ posv, float* __restrict__ out) {
  __shared__ float red[4];
  const int i = blockIdx.x * 256 + threadIdx.x;
  float S = 0.0f;
#pragma unroll
  for (int hh = 0; hh < 9; ++hh) S += rowpart[(size_t)hh * NROW + i];
#pragma unroll
  for (int ss = 0; ss < 32; ++ss) S += colpart[(size_t)ss * NROW + i];
  float l = __logf(S) + (1.0f - posv[i]) * INV_T;
#pragma unroll
  for (int off = 32; off > 0; off >>= 1) l += __shfl_down(l, off);
  if ((threadIdx.x & 63) == 0) red[threadIdx.x >> 6] = l;
  __syncthreads();
  if (threadIdx.x == 0)
    atomicAdd(out, (red[0] + red[1] + red[2] + red[3]) * (1.0f / NROW));
}

// ---------------------------------------------------------------------------
extern "C" void kernel_launch(void* const* d_in, const int* in_sizes, int n_in,
                              void* d_out, int out_size, void* d_ws, size_t ws_size,
                              hipStream_t stream) {
  const float* v1 = (const float*)d_in[0];
  const float* v2 = (const float*)d_in[1];
  float* out = (float*)d_out;

  __hip_bfloat16* e = (__hip_bfloat16*)d_ws;          // NROW*DIM bf16 (2 MB)
  float* rowpart = (float*)(e + (size_t)NROW * DIM);  // 9*NROW floats
  float* colpart = rowpart + (size_t)9 * NROW;        // 32*NROW floats
  float* posv    = colpart + (size_t)32 * NROW;       // NROW floats

  normalize_kernel<<<NROW / 4, 256, 0, stream>>>(v1, v2, e, rowpart, colpart,
                                                 out);
  dim3 grid(64, 9);
  sim_kernel<<<grid, 256, 0, stream>>>((const ushort*)e, rowpart, colpart,
                                       posv);
  finalize_kernel<<<32, 256, 0, stream>>>(rowpart, colpart, posv, out);
}

// Round 8
// 83.488 us; speedup vs baseline: 1.3219x; 1.3219x over previous
//
#include <hip/hip_runtime.h>
#include <hip/hip_bf16.h>
#include <math.h>

// Problem constants (fixed by reference setup_inputs)
#define BHALF 4096          // B
#define NROW 8192           // 2B
#define DIM 128             // D
#define INV_T 10.0f         // 1/temperature
#define K1 14.4269504088896f  // INV_T*log2(e): exp((v-1)*10) = 2^(v*K1 - K1)
#define LDB 136             // LDS col stride (ushorts) - 2-way bank alias = free (m136)

typedef short bf16x8 __attribute__((ext_vector_type(8)));   // 8 bf16 = 4 VGPRs
typedef float f32x4  __attribute__((ext_vector_type(4)));   // C/D frag

// ---------------------------------------------------------------------------
// Kernel 1: row-normalize concat(view1, view2) -> e_bf16 (NROW x DIM);
// zero expsum and d_out. One wave per row.  (R0 champion, verbatim.)
// ---------------------------------------------------------------------------
__global__ __launch_bounds__(256) void normalize_kernel(
    const float* __restrict__ v1, const float* __restrict__ v2,
    __hip_bfloat16* __restrict__ e, float* __restrict__ expsum,
    float* __restrict__ out) {
  int row  = blockIdx.x * 4 + (threadIdx.x >> 6);
  int lane = threadIdx.x & 63;
  const float* src = (row < BHALF) ? (v1 + (size_t)row * DIM)
                                   : (v2 + (size_t)(row - BHALF) * DIM);
  float2 x = ((const float2*)src)[lane];
  float ss = x.x * x.x + x.y * x.y;
#pragma unroll
  for (int off = 32; off > 0; off >>= 1) ss += __shfl_down(ss, off);
  ss = __shfl(ss, 0);
  float s = 1.0f / fmaxf(sqrtf(ss), 1e-8f);
  ((__hip_bfloat162*)(e + (size_t)row * DIM))[lane] =
      __float22bfloat162_rn(make_float2(x.x * s, x.y * s));
  if (lane == 0) expsum[row] = 0.0f;
  if (blockIdx.x == 0 && threadIdx.x == 0) out[0] = 0.0f;
}

// ---------------------------------------------------------------------------
// Symmetric MFMA sweep over one 128x128 tile (rows: strip r, cols: strip c).
// MODE 0: diagonal tile (r==c): full tile, mask col==row, row-sums only.
// MODE 1: off-diag pair: each exp feeds row-sum AND col-sum (symmetry).
// MODE 2: partner tile (c == r^32): local-diagonal = positives, weight 2
//         (denominator col-0 term + unmasked negative), posv for BOTH rows.
// R13 change vs champion: col-sums accumulate in csum8[8] REGISTERS (static
// index via FULL sub unroll); the 2-serial-shuffle + atomic per sub (R10
// PMC: 4.26M LDS-pipe conflict cycles, dependent chains in the hot loop)
// moves to the caller, once per tile, as 8 independent chains. Full unroll
// also makes ds_read offsets immediates (R10: ~120 VALU/sub was address
// recompute). Spill guard (R12 lesson): launch_bounds(256,2) -> 128-VGPR
// cap; this body needs ~85 arch VGPRs.
// ---------------------------------------------------------------------------
template <int MODE>
__device__ __forceinline__ void sweep_tile(
    const ushort* __restrict__ Bs, const bf16x8 (&a_frag)[2][4],
    float (&rsum)[2][4], float (&csum8)[8],
    float* __restrict__ posv, int wave, int lane, int n, int quad,
    int rowStrip, int colStrip) {
  const int colBase = colStrip * 128;
  const ushort* bpBase = &Bs[n * LDB + quad * 8];
#pragma unroll
  for (int sub = 0; sub < 8; ++sub) {
    const ushort* bp = bpBase + sub * 16 * LDB;   // immediate after unroll
    bf16x8 b[4];
#pragma unroll
    for (int kk = 0; kk < 4; ++kk) b[kk] = *(const bf16x8*)(bp + kk * 32);
    const int lc = sub * 16 + n;
#pragma unroll
    for (int rf = 0; rf < 2; ++rf) {
      f32x4 acc = {0.f, 0.f, 0.f, 0.f};
#pragma unroll
      for (int kk = 0; kk < 4; ++kk)
        acc = __builtin_amdgcn_mfma_f32_16x16x32_bf16(a_frag[rf][kk], b[kk],
                                                      acc, 0, 0, 0);
      // C layout: row = quad*4 + reg, col = lane&15 (m89/m91 verified).
#pragma unroll
      for (int rr = 0; rr < 4; ++rr) {
        const int lr = wave * 32 + rf * 16 + quad * 4 + rr;
        const float val = acc[rr];
        // exp((val-1)/T) = 2^(val*K1 - K1): one v_fma + one v_exp_f32
        const float ex = __builtin_amdgcn_exp2f(__builtin_fmaf(val, K1, -K1));
        if (MODE == 0) {
          rsum[rf][rr] += (lr == lc) ? 0.0f : ex;       // mask true diagonal
        } else if (MODE == 1) {
          rsum[rf][rr] += ex;
          csum8[sub] += ex;
        } else {                                        // partner tile
          const bool hit = (lr == lc);
          const float w = hit ? 2.0f : 1.0f;
          rsum[rf][rr] += w * ex;
          csum8[sub] += w * ex;
          if (hit) {
            posv[rowStrip * 128 + lr] = val;            // row i
            posv[colBase + lc] = val;                   // partner j = i^4096
          }
        }
      }
    }
  }
}

// ---------------------------------------------------------------------------
// Kernel 2: symmetric sim + online exp-sum. Grid (64, 33): x = row strip,
// y = cyclic offset d; col strip = (r+d)&63. d=32 valid only for r<32.
// Block: 4 waves; wave w owns rows [r*128 + w*32, +32) with A register-
// resident; 128 cols of strip c staged once in LDS (shared by 4 waves).
// Champion structure (uint4 reg staging + LDB pad + atomic epilogues:
// every replacement tried in R6-R12 measured equal or worse).
// ---------------------------------------------------------------------------
__global__ __launch_bounds__(256, 2) void sim_kernel(
    const ushort* __restrict__ e, float* __restrict__ expsum,
    float* __restrict__ posv) {
  const int r = blockIdx.x;
  const int d = blockIdx.y;
  if (d == 32 && r >= 32) return;   // uniform: whole block exits, no barrier hazard
  const int c = (r + d) & 63;

  __shared__ ushort Bs[128 * LDB] __attribute__((aligned(16)));

  const int tid  = threadIdx.x;
  const int wave = tid >> 6;
  const int lane = tid & 63;
  const int n    = lane & 15;
  const int quad = lane >> 4;

  // Stage col strip: 128 rows of E x 256 B, coalesced uint4.
#pragma unroll
  for (int u = 0; u < 8; ++u) {
    int idx = tid + 256 * u;
    int cc  = idx >> 4;
    int q4  = idx & 15;
    *(uint4*)(&Bs[cc * LDB + q4 * 8]) =
        *(const uint4*)(e + (size_t)(c * 128 + cc) * DIM + q4 * 8);
  }

  // A fragments: 2 row-frags x 4 k-steps, register-resident.
  bf16x8 a_frag[2][4];
  const int rowWave = r * 128 + wave * 32;
#pragma unroll
  for (int rf = 0; rf < 2; ++rf) {
    const ushort* rp = e + (size_t)(rowWave + rf * 16 + n) * DIM + quad * 8;
#pragma unroll
    for (int kk = 0; kk < 4; ++kk)
      a_frag[rf][kk] = *(const bf16x8*)(rp + kk * 32);
  }

  float rsum[2][4] = {{0.f, 0.f, 0.f, 0.f}, {0.f, 0.f, 0.f, 0.f}};
  float csum8[8] = {0.f, 0.f, 0.f, 0.f, 0.f, 0.f, 0.f, 0.f};
  __syncthreads();

  if (d == 0)
    sweep_tile<0>(Bs, a_frag, rsum, csum8, posv, wave, lane, n, quad, r, c);
  else if (d == 32)
    sweep_tile<2>(Bs, a_frag, rsum, csum8, posv, wave, lane, n, quad, r, c);
  else
    sweep_tile<1>(Bs, a_frag, rsum, csum8, posv, wave, lane, n, quad, r, c);

  // Col sums (d!=0): 8 independent 2-deep shuffle chains, one atomic each.
  if (d != 0) {
#pragma unroll
    for (int sub = 0; sub < 8; ++sub) {
      float v = csum8[sub];
      v += __shfl_xor(v, 16);
      v += __shfl_xor(v, 32);
      if (lane < 16) atomicAdd(&expsum[c * 128 + sub * 16 + n], v);
    }
  }

  // Row sums: reduce across the 16 col-lanes, one atomic per row.
#pragma unroll
  for (int rf = 0; rf < 2; ++rf)
#pragma unroll
    for (int rr = 0; rr < 4; ++rr) {
      float v = rsum[rf][rr];
      v += __shfl_xor(v, 1);
      v += __shfl_xor(v, 2);
      v += __shfl_xor(v, 4);
      v += __shfl_xor(v, 8);
      if (n == 0) atomicAdd(&expsum[rowWave + rf * 16 + quad * 4 + rr], v);
    }
}

// ---------------------------------------------------------------------------
// Kernel 3: loss_i = log(S_i) + (1 - pos_i)/T ; out = mean (atomic partials).
// 32 blocks x 256 threads, one row per thread.  (R0 champion, verbatim.)
// ---------------------------------------------------------------------------
__global__ __launch_bounds__(256) void finalize_kernel(
    const float* __restrict__ expsum, const float* __restrict__ posv,
    float* __restrict__ out) {
  __shared__ float red[4];
  const int i = blockIdx.x * 256 + threadIdx.x;
  float l = __logf(expsum[i]) + (1.0f - posv[i]) * INV_T;
#pragma unroll
  for (int off = 32; off > 0; off >>= 1) l += __shfl_down(l, off);
  if ((threadIdx.x & 63) == 0) red[threadIdx.x >> 6] = l;
  __syncthreads();
  if (threadIdx.x == 0)
    atomicAdd(out, (red[0] + red[1] + red[2] + red[3]) * (1.0f / NROW));
}

// ---------------------------------------------------------------------------
extern "C" void kernel_launch(void* const* d_in, const int* in_sizes, int n_in,
                              void* d_out, int out_size, void* d_ws, size_t ws_size,
                              hipStream_t stream) {
  const float* v1 = (const float*)d_in[0];
  const float* v2 = (const float*)d_in[1];
  float* out = (float*)d_out;

  __hip_bfloat16* e = (__hip_bfloat16*)d_ws;          // NROW*DIM bf16 (2 MB)
  float* expsum = (float*)(e + (size_t)NROW * DIM);   // NROW floats
  float* posv   = expsum + NROW;                      // NROW floats

  normalize_kernel<<<NROW / 4, 256, 0, stream>>>(v1, v2, e, expsum, out);
  dim3 grid(64, 33);
  sim_kernel<<<grid, 256, 0, stream>>>((const ushort*)e, expsum, posv);
  finalize_kernel<<<32, 256, 0, stream>>>(expsum, posv, out);
}